// Round 17
// baseline (729.776 us; speedup 1.0000x reference)
//
#include <hip/hip_runtime.h>
#include <hip/hip_bf16.h>
#include <stdint.h>

typedef __attribute__((ext_vector_type(8))) short short8;
typedef __attribute__((ext_vector_type(4))) float f32x4;
typedef __attribute__((ext_vector_type(4))) int int4v;

__device__ __forceinline__ unsigned short f2bf(float f) {
    union { float f; uint32_t u; } v; v.f = f;
    return (unsigned short)((v.u + 0x7FFFu + ((v.u >> 16) & 1u)) >> 16);
}

// Build W in MFMA-FRAGMENT order with the LINE-COALESCED k-map (R13):
//   lane (l15,lhi), elem e holds k = c*32 + (e<4 ? lhi*4+e : 16+lhi*4+(e-4))
//   Wfrag[((ct*6 + c)*64 + lane)*8 + e] = bf16( W[ct*16 + (lane&15)][k] )
// where W[j][k] = kernel[cayley[inv[k>>4], j>>4]][j&15][k&15].
// The (lane,e)->k permutation is shared by A(x) and B(W) so it cancels in MFMA.
__global__ void build_w_kernel(const float* __restrict__ kern,
                               const int* __restrict__ cayley,
                               const int* __restrict__ inv,
                               unsigned short* __restrict__ Wfrag) {
    int i = blockIdx.x * blockDim.x + threadIdx.x;   // i = ((ct*6+c)*64 + lane)*8 + e
    if (i >= 192 * 192) return;
    int e    = i & 7;
    int lane = (i >> 3) & 63;
    int fc   = i >> 9;            // ct*6 + c
    int ct   = fc / 6, c = fc - ct * 6;
    int j = ct * 16 + (lane & 15);
    int lhi = lane >> 4;
    int k = c * 32 + ((e < 4) ? (lhi * 4 + e) : (16 + lhi * 4 + (e - 4)));
    int h = j >> 4, oc = j & 15;
    int g = k >> 4, ic = k & 15;
    int cidx = cayley[inv[g] * 12 + h];
    Wfrag[i] = f2bf(kern[cidx * 256 + oc * 16 + ic]);
}

// out[n][j] = sum_k x[n][k] * W[j][k] + bias[j]
// R16: UNCAGED. FETCH-ledger audit: every spill round had a register CAP +
// scheduling freedom (R2/R6/R7/R8 dirty FETCH ~600-800MB); every uncapped
// round was spill-free (R4: 224 VGPR, FETCH 198MB). Occupancy is proven
// irrelevant (11..43% flat). So: NO __launch_bounds__, NO sched_barrier —
// the lean body (LDS W, 48-reg staging, 1-deep prefetch) compiles bare to
// ~140-200 VGPR spill-free and the compiler schedules across strip bounds.
// Keep: fragment-order LDS W (0 conflicts), line-coalesced k-map, swapped
// MFMA, plain dwordx4 stores (NT was +22us), manual 1-deep x prefetch.
__global__ void gemm_kernel(
    const float* __restrict__ x,
    const unsigned short* __restrict__ Wfrag,
    const float* __restrict__ bias,
    float* __restrict__ out, int nstrips, int spw) {
  __shared__ unsigned char lds[192 * 192 * 2];   // 73728 B, fragment order
  const int tid  = threadIdx.x;
  const int lane = tid & 63;
  const int wid  = tid >> 6;
  const int l15  = lane & 15;
  const int lhi  = lane >> 4;

  // Stage W fragments into LDS (pure linear copy, 73728 B / 512 thr = 9 x int4).
  {
    const int4v* src = (const int4v*)Wfrag;
    int4v* dst = (int4v*)lds;
    #pragma unroll
    for (int t = 0; t < 9; ++t) dst[tid + t * 512] = src[tid + t * 512];
  }
  __syncthreads();

  const int gw = blockIdx.x * 8 + wid;    // global wave id
  int strip = gw * spw;
  const int send = min(strip + spw, nstrips);
  if (strip >= send) return;

  // bias for this lane's 4 output features (j = ct*16 + lhi*4 + r)
  const f32x4 bias4 = *(const f32x4*)(bias + lhi * 4);
  // LDS fragment base for this lane: frag (ct,c) at lane*16 + (ct*6+c)*1024
  const unsigned char* wbase = lds + lane * 16;

  // Prologue: issue strip 0's loads.
  f32x4 fa[6], fb[6];
  {
    const float* xr = x + (size_t)(strip * 16 + l15) * 192 + lhi * 4;
    #pragma unroll
    for (int c = 0; c < 6; ++c) {
      fa[c] = *(const f32x4*)(xr + c * 32);        // k = c*32 + lhi*4 + 0..3
      fb[c] = *(const f32x4*)(xr + c * 32 + 16);   // k = c*32 + 16 + lhi*4 + 0..3
    }
  }

  while (strip < send) {
    // Wait for this strip's loads; convert (frees fa/fb for reuse).
    short8 abf[6];
    #pragma unroll
    for (int c = 0; c < 6; ++c) {
      short8 v;
      #pragma unroll
      for (int e = 0; e < 4; ++e) {
        v[e]     = (short)f2bf(fa[c][e]);
        v[e + 4] = (short)f2bf(fb[c][e]);
      }
      abf[c] = v;
    }

    // Issue NEXT strip's loads now; compute below covers the latency.
    const int nxt = strip + 1;
    if (nxt < send) {
      const float* xr = x + (size_t)(nxt * 16 + l15) * 192 + lhi * 4;
      #pragma unroll
      for (int c = 0; c < 6; ++c) {
        fa[c] = *(const f32x4*)(xr + c * 32);
        fb[c] = *(const f32x4*)(xr + c * 32 + 16);
      }
    }

    float* obase = out + (size_t)(strip * 16 + l15) * 192 + lhi * 4;
    #pragma unroll
    for (int cp = 0; cp < 6; ++cp) {           // ct-pair: cts {2cp, 2cp+1}
      short8 wf0[6], wf1[6];
      #pragma unroll
      for (int c = 0; c < 6; ++c) wf0[c] = *(const short8*)(wbase + (cp * 12 + c) * 1024);
      f32x4 acc0 = {0.f, 0.f, 0.f, 0.f};
      #pragma unroll
      for (int c = 0; c < 6; ++c)
        acc0 = __builtin_amdgcn_mfma_f32_16x16x32_bf16(wf0[c], abf[c], acc0, 0, 0, 0);
      #pragma unroll
      for (int c = 0; c < 6; ++c) wf1[c] = *(const short8*)(wbase + (cp * 12 + 6 + c) * 1024);
      f32x4 acc1 = {0.f, 0.f, 0.f, 0.f};
      #pragma unroll
      for (int c = 0; c < 6; ++c)
        acc1 = __builtin_amdgcn_mfma_f32_16x16x32_bf16(wf1[c], abf[c], acc1, 0, 0, 0);
      f32x4 r0 = {acc0[0] + bias4[0], acc0[1] + bias4[1],
                  acc0[2] + bias4[2], acc0[3] + bias4[3]};
      f32x4 r1 = {acc1[0] + bias4[0], acc1[1] + bias4[1],
                  acc1[2] + bias4[2], acc1[3] + bias4[3]};
      *(f32x4*)(obase + (2 * cp) * 16)     = r0;
      *(f32x4*)(obase + (2 * cp + 1) * 16) = r1;
    }
    strip = nxt;
  }
}

extern "C" void kernel_launch(void* const* d_in, const int* in_sizes, int n_in,
                              void* d_out, int out_size, void* d_ws, size_t ws_size,
                              hipStream_t stream) {
    const float* x      = (const float*)d_in[0];
    const float* kern   = (const float*)d_in[1];
    const float* bias   = (const float*)d_in[2];
    const int*   cayley = (const int*)d_in[3];
    const int*   inv    = (const int*)d_in[4];
    float* out = (float*)d_out;
    unsigned short* Wfrag = (unsigned short*)d_ws;   // 73728 bytes

    const int nrows = in_sizes[0] / 192;
    const int nstrips = nrows / 16;                  // 32768

    build_w_kernel<<<(192 * 192 + 255) / 256, 256, 0, stream>>>(kern, cayley, inv, Wfrag);

    const int nblocks = 512;                         // persistent, 2 blocks/CU (LDS)
    const int nwaves  = nblocks * 8;                 // 4096 waves
    const int spw     = (nstrips + nwaves - 1) / nwaves;   // = 8
    gemm_kernel<<<nblocks, 512, 0, stream>>>(x, Wfrag, bias, out, nstrips, spw);
}

// Round 18
// 590.305 us; speedup vs baseline: 1.2363x; 1.2363x over previous
//
#include <hip/hip_runtime.h>
#include <hip/hip_bf16.h>
#include <stdint.h>

typedef __attribute__((ext_vector_type(8))) short short8;
typedef __attribute__((ext_vector_type(4))) float f32x4;
typedef __attribute__((ext_vector_type(4))) int int4v;

__device__ __forceinline__ unsigned short f2bf(float f) {
    union { float f; uint32_t u; } v; v.f = f;
    return (unsigned short)((v.u + 0x7FFFu + ((v.u >> 16) & 1u)) >> 16);
}

// Build W in MFMA-FRAGMENT order with the LINE-COALESCED k-map (R13):
//   lane (l15,lhi), elem e holds k = c*32 + (e<4 ? lhi*4+e : 16+lhi*4+(e-4))
//   Wfrag[((ct*6 + c)*64 + lane)*8 + e] = bf16( W[ct*16 + (lane&15)][k] )
// where W[j][k] = kernel[cayley[inv[k>>4], j>>4]][j&15][k&15].
// The (lane,e)->k permutation is shared by A(x) and B(W) so it cancels in MFMA.
__global__ void build_w_kernel(const float* __restrict__ kern,
                               const int* __restrict__ cayley,
                               const int* __restrict__ inv,
                               unsigned short* __restrict__ Wfrag) {
    int i = blockIdx.x * blockDim.x + threadIdx.x;   // i = ((ct*6+c)*64 + lane)*8 + e
    if (i >= 192 * 192) return;
    int e    = i & 7;
    int lane = (i >> 3) & 63;
    int fc   = i >> 9;            // ct*6 + c
    int ct   = fc / 6, c = fc - ct * 6;
    int j = ct * 16 + (lane & 15);
    int lhi = lane >> 4;
    int k = c * 32 + ((e < 4) ? (lhi * 4 + e) : (16 + lhi * 4 + (e - 4)));
    int h = j >> 4, oc = j & 15;
    int g = k >> 4, ic = k & 15;
    int cidx = cayley[inv[g] * 12 + h];
    Wfrag[i] = f2bf(kern[cidx * 256 + oc * 16 + ic]);
}

// out[n][j] = sum_k x[n][k] * W[j][k] + bias[j]
// R17: DEPTH-2 software pipeline (last untested axis: MLP depth / queue never
// drains). Two staging buffers; per iter wait only the OLDER buffer's loads
// (12 newer loads + 12 stores remain in flight across the wait), cvt, reissue
// that buffer 2 strips ahead, compute+store. (512,1) => 256-VGPR budget: the
// R16 lesson is bare+LDS defaults to 64 and spills; explicit generous cap is
// the only spill-free fat-body config. Occupancy ~3 waves/SIMD (proven
// irrelevant: 11..47% flat). Keep: fragment-order LDS W (0 conflicts),
// line-coalesced k-map, swapped MFMA, ct-pair compute, paired plain stores.
__global__ __launch_bounds__(512, 1) void gemm_kernel(
    const float* __restrict__ x,
    const unsigned short* __restrict__ Wfrag,
    const float* __restrict__ bias,
    float* __restrict__ out, int nstrips, int spw) {
  __shared__ unsigned char lds[192 * 192 * 2];   // 73728 B, fragment order
  const int tid  = threadIdx.x;
  const int lane = tid & 63;
  const int wid  = tid >> 6;
  const int l15  = lane & 15;
  const int lhi  = lane >> 4;

  // Stage W fragments into LDS (pure linear copy, 73728 B / 512 thr = 9 x int4).
  {
    const int4v* src = (const int4v*)Wfrag;
    int4v* dst = (int4v*)lds;
    #pragma unroll
    for (int t = 0; t < 9; ++t) dst[tid + t * 512] = src[tid + t * 512];
  }
  __syncthreads();

  const int gw = blockIdx.x * 8 + wid;    // global wave id
  const int s0 = gw * spw;
  const int send = min(s0 + spw, nstrips);
  if (s0 >= send) return;

  // bias for this lane's 4 output features (j = ct*16 + lhi*4 + r)
  const f32x4 bias4 = *(const f32x4*)(bias + lhi * 4);
  // LDS fragment base for this lane: frag (ct,c) at lane*16 + (ct*6+c)*1024
  const unsigned char* wbase = lds + lane * 16;
  // Per-lane x base offset within a strip: row l15, float offset lhi*4.
  const size_t xoff = (size_t)l15 * 192 + lhi * 4;

  // Staging buffers A and B (48 f32 regs each).
  f32x4 faA[6], fbA[6], faB[6], fbB[6];

  // Prologue: issue loads for strips s0 (-> A) and s0+1 (-> B).
  {
    const float* xr = x + (size_t)s0 * 16 * 192 + xoff;
    #pragma unroll
    for (int c = 0; c < 6; ++c) {
      faA[c] = *(const f32x4*)(xr + c * 32);
      fbA[c] = *(const f32x4*)(xr + c * 32 + 16);
    }
  }
  if (s0 + 1 < send) {
    const float* xr = x + (size_t)(s0 + 1) * 16 * 192 + xoff;
    #pragma unroll
    for (int c = 0; c < 6; ++c) {
      faB[c] = *(const f32x4*)(xr + c * 32);
      fbB[c] = *(const f32x4*)(xr + c * 32 + 16);
    }
  }

  for (int strip = s0; strip < send; ++strip) {
    const bool useA = ((strip - s0) & 1) == 0;

    // cvt from the older buffer (waits only its 12 loads; the other buffer's
    // 12 loads and last strip's 12 stores stay in flight).
    short8 abf[6];
    #pragma unroll
    for (int c = 0; c < 6; ++c) {
      f32x4 lo = useA ? faA[c] : faB[c];
      f32x4 hi = useA ? fbA[c] : fbB[c];
      short8 v;
      #pragma unroll
      for (int e = 0; e < 4; ++e) {
        v[e]     = (short)f2bf(lo[e]);
        v[e + 4] = (short)f2bf(hi[e]);
      }
      abf[c] = v;
    }

    // Reissue the just-freed buffer 2 strips ahead.
    const int pf = strip + 2;
    if (pf < send) {
      const float* xr = x + (size_t)pf * 16 * 192 + xoff;
      if (useA) {
        #pragma unroll
        for (int c = 0; c < 6; ++c) {
          faA[c] = *(const f32x4*)(xr + c * 32);
          fbA[c] = *(const f32x4*)(xr + c * 32 + 16);
        }
      } else {
        #pragma unroll
        for (int c = 0; c < 6; ++c) {
          faB[c] = *(const f32x4*)(xr + c * 32);
          fbB[c] = *(const f32x4*)(xr + c * 32 + 16);
        }
      }
    }

    float* obase = out + (size_t)(strip * 16 + l15) * 192 + lhi * 4;
    #pragma unroll
    for (int cp = 0; cp < 6; ++cp) {           // ct-pair: cts {2cp, 2cp+1}
      short8 wf0[6], wf1[6];
      #pragma unroll
      for (int c = 0; c < 6; ++c) wf0[c] = *(const short8*)(wbase + (cp * 12 + c) * 1024);
      f32x4 acc0 = {0.f, 0.f, 0.f, 0.f};
      #pragma unroll
      for (int c = 0; c < 6; ++c)
        acc0 = __builtin_amdgcn_mfma_f32_16x16x32_bf16(wf0[c], abf[c], acc0, 0, 0, 0);
      #pragma unroll
      for (int c = 0; c < 6; ++c) wf1[c] = *(const short8*)(wbase + (cp * 12 + 6 + c) * 1024);
      f32x4 acc1 = {0.f, 0.f, 0.f, 0.f};
      #pragma unroll
      for (int c = 0; c < 6; ++c)
        acc1 = __builtin_amdgcn_mfma_f32_16x16x32_bf16(wf1[c], abf[c], acc1, 0, 0, 0);
      f32x4 r0 = {acc0[0] + bias4[0], acc0[1] + bias4[1],
                  acc0[2] + bias4[2], acc0[3] + bias4[3]};
      f32x4 r1 = {acc1[0] + bias4[0], acc1[1] + bias4[1],
                  acc1[2] + bias4[2], acc1[3] + bias4[3]};
      *(f32x4*)(obase + (2 * cp) * 16)     = r0;   // adjacent halves -> full 128B sector
      *(f32x4*)(obase + (2 * cp + 1) * 16) = r1;
    }
  }
}

extern "C" void kernel_launch(void* const* d_in, const int* in_sizes, int n_in,
                              void* d_out, int out_size, void* d_ws, size_t ws_size,
                              hipStream_t stream) {
    const float* x      = (const float*)d_in[0];
    const float* kern   = (const float*)d_in[1];
    const float* bias   = (const float*)d_in[2];
    const int*   cayley = (const int*)d_in[3];
    const int*   inv    = (const int*)d_in[4];
    float* out = (float*)d_out;
    unsigned short* Wfrag = (unsigned short*)d_ws;   // 73728 bytes

    const int nrows = in_sizes[0] / 192;
    const int nstrips = nrows / 16;                  // 32768

    build_w_kernel<<<(192 * 192 + 255) / 256, 256, 0, stream>>>(kern, cayley, inv, Wfrag);

    const int nblocks = 512;                         // persistent, 2 blocks/CU (LDS)
    const int nwaves  = nblocks * 8;                 // 4096 waves
    const int spw     = (nstrips + nwaves - 1) / nwaves;   // = 8
    gemm_kernel<<<nblocks, 512, 0, stream>>>(x, Wfrag, bias, out, nstrips, spw);
}

// Round 19
// 508.963 us; speedup vs baseline: 1.4338x; 1.1598x over previous
//
#include <hip/hip_runtime.h>
#include <hip/hip_bf16.h>
#include <stdint.h>

typedef __attribute__((ext_vector_type(8))) short short8;
typedef __attribute__((ext_vector_type(4))) float f32x4;

__device__ __forceinline__ unsigned short f2bf(float f) {
    union { float f; uint32_t u; } v; v.f = f;
    return (unsigned short)((v.u + 0x7FFFu + ((v.u >> 16) & 1u)) >> 16);
}

// Build W in MFMA-FRAGMENT order with the LINE-COALESCED k-map (R13):
//   lane (l15,lhi), elem e holds k = c*32 + (e<4 ? lhi*4+e : 16+lhi*4+(e-4))
//   Wfrag[((ct*6 + c)*64 + lane)*8 + e] = bf16( W[ct*16 + (lane&15)][k] )
// where W[j][k] = kernel[cayley[inv[k>>4], j>>4]][j&15][k&15].
// The (lane,e)->k permutation is shared by A(x) and B(W) so it cancels in MFMA.
__global__ void build_w_kernel(const float* __restrict__ kern,
                               const int* __restrict__ cayley,
                               const int* __restrict__ inv,
                               unsigned short* __restrict__ Wfrag) {
    int i = blockIdx.x * blockDim.x + threadIdx.x;   // i = ((ct*6+c)*64 + lane)*8 + e
    if (i >= 192 * 192) return;
    int e    = i & 7;
    int lane = (i >> 3) & 63;
    int fc   = i >> 9;            // ct*6 + c
    int ct   = fc / 6, c = fc - ct * 6;
    int j = ct * 16 + (lane & 15);
    int lhi = lane >> 4;
    int k = c * 32 + ((e < 4) ? (lhi * 4 + e) : (16 + lhi * 4 + (e - 4)));
    int h = j >> 4, oc = j & 15;
    int g = k >> 4, ic = k & 15;
    int cidx = cayley[inv[g] * 12 + h];
    Wfrag[i] = f2bf(kern[cidx * 256 + oc * 16 + ic]);
}

// out[n][j] = sum_k x[n][k] * W[j][k] + bias[j]
// R18: W ENTIRELY IN REGISTERS — zero LDS, zero W traffic in the loop; vmem is
// a pure x-load / out-store stream (closest-to-copy structure). The 12 ct's
// split 3-per-wave across the block's 4 waves (18 frags = 72 VGPR/wave); all
// 4 waves process the SAME strip, so x is fetched once from HBM + 3x from L2
// (extra 1.2 GB L2 reads ~= 35us of L2 time, far under its ceiling). The 4
// waves jointly write all 192 cols of each row in adjacent 64B chunks.
// No __launch_bounds__: R17 proved (512,1) still caps at 128 with LDS; the
// no-LDS bare precedent (R4: 224 VGPR, FETCH clean 198 MB) is spill-free.
// Keep: line-coalesced k-map, swapped MFMA, 1-deep x prefetch, plain stores.
__global__ void gemm_kernel(
    const float* __restrict__ x,
    const unsigned short* __restrict__ Wfrag,
    const float* __restrict__ bias,
    float* __restrict__ out, int nstrips, int spb) {
  const int tid  = threadIdx.x;
  const int lane = tid & 63;
  const int wid  = tid >> 6;          // 0..3 -> owns cts [3*wid, 3*wid+3)
  const int l15  = lane & 15;
  const int lhi  = lane >> 4;

  // Load this wave's 18 W fragments into registers (one-time, L2-resident).
  short8 wf[3][6];
  #pragma unroll
  for (int t = 0; t < 3; ++t)
    #pragma unroll
    for (int c = 0; c < 6; ++c)
      wf[t][c] = *(const short8*)(Wfrag + (((wid * 3 + t) * 6 + c) * 64 + lane) * 8);

  // bias for this lane's 4 output features (j = ct*16 + lhi*4 + r -> oc = lhi*4+r)
  const f32x4 bias4 = *(const f32x4*)(bias + lhi * 4);

  int strip = blockIdx.x * spb;
  const int send = min(strip + spb, nstrips);
  if (strip >= send) return;

  // Per-lane x offset within a strip: row l15, float offset lhi*4.
  const size_t xoff = (size_t)l15 * 192 + lhi * 4;

  // Prologue: issue strip 0's loads (line-coalesced k-map: two 16B chunks
  // per 128B c-window, lanes lhi=0..3 covering each 64B line fully).
  f32x4 fa[6], fb[6];
  {
    const float* xr = x + (size_t)strip * 16 * 192 + xoff;
    #pragma unroll
    for (int c = 0; c < 6; ++c) {
      fa[c] = *(const f32x4*)(xr + c * 32);
      fb[c] = *(const f32x4*)(xr + c * 32 + 16);
    }
  }

  while (strip < send) {
    // Wait this strip's loads; convert (frees fa/fb).
    short8 abf[6];
    #pragma unroll
    for (int c = 0; c < 6; ++c) {
      short8 v;
      #pragma unroll
      for (int e = 0; e < 4; ++e) {
        v[e]     = (short)f2bf(fa[c][e]);
        v[e + 4] = (short)f2bf(fb[c][e]);
      }
      abf[c] = v;
    }

    // Issue next strip's loads; compute below covers the latency.
    const int nxt = strip + 1;
    if (nxt < send) {
      const float* xr = x + (size_t)nxt * 16 * 192 + xoff;
      #pragma unroll
      for (int c = 0; c < 6; ++c) {
        fa[c] = *(const f32x4*)(xr + c * 32);
        fb[c] = *(const f32x4*)(xr + c * 32 + 16);
      }
    }

    // Compute + store this wave's 3 cts (48 of 192 cols, adjacent 64B chunks).
    float* obase = out + (size_t)(strip * 16 + l15) * 192 + lhi * 4;
    #pragma unroll
    for (int t = 0; t < 3; ++t) {
      f32x4 acc = {0.f, 0.f, 0.f, 0.f};
      #pragma unroll
      for (int c = 0; c < 6; ++c)
        acc = __builtin_amdgcn_mfma_f32_16x16x32_bf16(wf[t][c], abf[c], acc, 0, 0, 0);
      f32x4 res = {acc[0] + bias4[0], acc[1] + bias4[1],
                   acc[2] + bias4[2], acc[3] + bias4[3]};
      *(f32x4*)(obase + (wid * 3 + t) * 16) = res;
    }
    strip = nxt;
  }
}

extern "C" void kernel_launch(void* const* d_in, const int* in_sizes, int n_in,
                              void* d_out, int out_size, void* d_ws, size_t ws_size,
                              hipStream_t stream) {
    const float* x      = (const float*)d_in[0];
    const float* kern   = (const float*)d_in[1];
    const float* bias   = (const float*)d_in[2];
    const int*   cayley = (const int*)d_in[3];
    const int*   inv    = (const int*)d_in[4];
    float* out = (float*)d_out;
    unsigned short* Wfrag = (unsigned short*)d_ws;   // 73728 bytes

    const int nrows = in_sizes[0] / 192;
    const int nstrips = nrows / 16;                  // 32768

    build_w_kernel<<<(192 * 192 + 255) / 256, 256, 0, stream>>>(kern, cayley, inv, Wfrag);

    const int nblocks = 1024;                        // persistent, no LDS
    const int spb     = (nstrips + nblocks - 1) / nblocks;   // strips per block = 32
    gemm_kernel<<<nblocks, 256, 0, stream>>>(x, Wfrag, bias, out, nstrips, spb);
}

// Round 20
// 258.409 us; speedup vs baseline: 2.8241x; 1.9696x over previous
//
#include <hip/hip_runtime.h>
#include <hip/hip_bf16.h>
#include <stdint.h>

typedef __attribute__((ext_vector_type(8))) short short8;
typedef __attribute__((ext_vector_type(4))) float f32x4;

__device__ __forceinline__ unsigned short f2bf(float f) {
    union { float f; uint32_t u; } v; v.f = f;
    return (unsigned short)((v.u + 0x7FFFu + ((v.u >> 16) & 1u)) >> 16);
}

// Build W in MFMA-FRAGMENT order with the LINE-COALESCED k-map (R13):
//   lane (l15,lhi), elem e holds k = c*32 + (e<4 ? lhi*4+e : 16+lhi*4+(e-4))
//   Wfrag[((ct*6 + c)*64 + lane)*8 + e] = bf16( W[ct*16 + (lane&15)][k] )
// where W[j][k] = kernel[cayley[inv[k>>4], j>>4]][j&15][k&15].
// The (lane,e)->k permutation is shared by A(x) and B(W) so it cancels in MFMA.
__global__ void build_w_kernel(const float* __restrict__ kern,
                               const int* __restrict__ cayley,
                               const int* __restrict__ inv,
                               unsigned short* __restrict__ Wfrag) {
    int i = blockIdx.x * blockDim.x + threadIdx.x;   // i = ((ct*6+c)*64 + lane)*8 + e
    if (i >= 192 * 192) return;
    int e    = i & 7;
    int lane = (i >> 3) & 63;
    int fc   = i >> 9;            // ct*6 + c
    int ct   = fc / 6, c = fc - ct * 6;
    int j = ct * 16 + (lane & 15);
    int lhi = lane >> 4;
    int k = c * 32 + ((e < 4) ? (lhi * 4 + e) : (16 + lhi * 4 + (e - 4)));
    int h = j >> 4, oc = j & 15;
    int g = k >> 4, ic = k & 15;
    int cidx = cayley[inv[g] * 12 + h];
    Wfrag[i] = f2bf(kern[cidx * 256 + oc * 16 + ic]);
}

// out[n][j] = sum_k x[n][k] * W[j][k] + bias[j]
// R19 = R18 + __launch_bounds__(256,1). R18's bare allocation chose 64 VGPR
// (bare is a coin flip: R4->224, R16/R18->64) and spilled the ~160-live body.
// Ledger rule cap=256/arg2 has held for every 2-arg form; (256,1) => 256 cap
// on a no-LDS kernel. W ENTIRELY IN REGISTERS: 12 cts split 3-per-wave over
// 4 waves (18 frags = 72 VGPR); all 4 waves process the same strip (x: 1x HBM
// + 3x L2); the 4 waves jointly write all 192 cols in adjacent 64B chunks.
// vmem is a pure x-load/out-store stream — closest-to-copy structure.
// Keep: line-coalesced k-map, swapped MFMA, 1-deep x prefetch, plain stores.
__global__ __launch_bounds__(256, 1) void gemm_kernel(
    const float* __restrict__ x,
    const unsigned short* __restrict__ Wfrag,
    const float* __restrict__ bias,
    float* __restrict__ out, int nstrips, int spb) {
  const int tid  = threadIdx.x;
  const int lane = tid & 63;
  const int wid  = tid >> 6;          // 0..3 -> owns cts [3*wid, 3*wid+3)
  const int l15  = lane & 15;
  const int lhi  = lane >> 4;

  // Load this wave's 18 W fragments into registers (one-time, L2-resident).
  short8 wf[3][6];
  #pragma unroll
  for (int t = 0; t < 3; ++t)
    #pragma unroll
    for (int c = 0; c < 6; ++c)
      wf[t][c] = *(const short8*)(Wfrag + (((wid * 3 + t) * 6 + c) * 64 + lane) * 8);

  // bias for this lane's 4 output features (j = ct*16 + lhi*4 + r -> oc = lhi*4+r)
  const f32x4 bias4 = *(const f32x4*)(bias + lhi * 4);

  int strip = blockIdx.x * spb;
  const int send = min(strip + spb, nstrips);
  if (strip >= send) return;

  // Per-lane x offset within a strip: row l15, float offset lhi*4.
  const size_t xoff = (size_t)l15 * 192 + lhi * 4;

  // Prologue: issue strip 0's loads (line-coalesced k-map: two 16B chunks
  // per 128B c-window, lanes lhi=0..3 covering each 64B line fully).
  f32x4 fa[6], fb[6];
  {
    const float* xr = x + (size_t)strip * 16 * 192 + xoff;
    #pragma unroll
    for (int c = 0; c < 6; ++c) {
      fa[c] = *(const f32x4*)(xr + c * 32);
      fb[c] = *(const f32x4*)(xr + c * 32 + 16);
    }
  }

  while (strip < send) {
    // Wait this strip's loads; convert (frees fa/fb).
    short8 abf[6];
    #pragma unroll
    for (int c = 0; c < 6; ++c) {
      short8 v;
      #pragma unroll
      for (int e = 0; e < 4; ++e) {
        v[e]     = (short)f2bf(fa[c][e]);
        v[e + 4] = (short)f2bf(fb[c][e]);
      }
      abf[c] = v;
    }

    // Issue next strip's loads; compute below covers the latency.
    const int nxt = strip + 1;
    if (nxt < send) {
      const float* xr = x + (size_t)nxt * 16 * 192 + xoff;
      #pragma unroll
      for (int c = 0; c < 6; ++c) {
        fa[c] = *(const f32x4*)(xr + c * 32);
        fb[c] = *(const f32x4*)(xr + c * 32 + 16);
      }
    }

    // Compute + store this wave's 3 cts (48 of 192 cols, adjacent 64B chunks).
    float* obase = out + (size_t)(strip * 16 + l15) * 192 + lhi * 4;
    #pragma unroll
    for (int t = 0; t < 3; ++t) {
      f32x4 acc = {0.f, 0.f, 0.f, 0.f};
      #pragma unroll
      for (int c = 0; c < 6; ++c)
        acc = __builtin_amdgcn_mfma_f32_16x16x32_bf16(wf[t][c], abf[c], acc, 0, 0, 0);
      f32x4 res = {acc[0] + bias4[0], acc[1] + bias4[1],
                   acc[2] + bias4[2], acc[3] + bias4[3]};
      *(f32x4*)(obase + (wid * 3 + t) * 16) = res;
    }
    strip = nxt;
  }
}

extern "C" void kernel_launch(void* const* d_in, const int* in_sizes, int n_in,
                              void* d_out, int out_size, void* d_ws, size_t ws_size,
                              hipStream_t stream) {
    const float* x      = (const float*)d_in[0];
    const float* kern   = (const float*)d_in[1];
    const float* bias   = (const float*)d_in[2];
    const int*   cayley = (const int*)d_in[3];
    const int*   inv    = (const int*)d_in[4];
    float* out = (float*)d_out;
    unsigned short* Wfrag = (unsigned short*)d_ws;   // 73728 bytes

    const int nrows = in_sizes[0] / 192;
    const int nstrips = nrows / 16;                  // 32768

    build_w_kernel<<<(192 * 192 + 255) / 256, 256, 0, stream>>>(kern, cayley, inv, Wfrag);

    const int nblocks = 1024;                        // persistent, no LDS
    const int spb     = (nstrips + nblocks - 1) / nblocks;   // strips per block = 32
    gemm_kernel<<<nblocks, 256, 0, stream>>>(x, Wfrag, bias, out, nstrips, spb);
}

// Round 21
// 168.293 us; speedup vs baseline: 4.3363x; 1.5355x over previous
//
#include <hip/hip_runtime.h>
#include <hip/hip_bf16.h>
#include <stdint.h>

typedef __attribute__((ext_vector_type(8))) short short8;
typedef __attribute__((ext_vector_type(4))) float f32x4;

__device__ __forceinline__ unsigned short f2bf(float f) {
    union { float f; uint32_t u; } v; v.f = f;
    return (unsigned short)((v.u + 0x7FFFu + ((v.u >> 16) & 1u)) >> 16);
}

// Build W in MFMA-FRAGMENT order with the LINE-COALESCED k-map (R13, unchanged):
//   lane (l15,lhi), elem e holds k = c*32 + (e<4 ? lhi*4+e : 16+lhi*4+(e-4))
//   Wfrag[((ct*6 + c)*64 + lane)*8 + e] = bf16( W[ct*16 + (lane&15)][k] )
// where W[j][k] = kernel[cayley[inv[k>>4], j>>4]][j&15][k&15].
__global__ void build_w_kernel(const float* __restrict__ kern,
                               const int* __restrict__ cayley,
                               const int* __restrict__ inv,
                               unsigned short* __restrict__ Wfrag) {
    int i = blockIdx.x * blockDim.x + threadIdx.x;   // i = ((ct*6+c)*64 + lane)*8 + e
    if (i >= 192 * 192) return;
    int e    = i & 7;
    int lane = (i >> 3) & 63;
    int fc   = i >> 9;            // ct*6 + c
    int ct   = fc / 6, c = fc - ct * 6;
    int j = ct * 16 + (lane & 15);
    int lhi = lane >> 4;
    int k = c * 32 + ((e < 4) ? (lhi * 4 + e) : (16 + lhi * 4 + (e - 4)));
    int h = j >> 4, oc = j & 15;
    int g = k >> 4, ic = k & 15;
    int cidx = cayley[inv[g] * 12 + h];
    Wfrag[i] = f2bf(kern[cidx * 256 + oc * 16 + ic]);
}

// out[n][j] = sum_k x[n][k] * W[j][k] + bias[j]
// R20: COPY-SHAPED GLOBAL INSTRUCTIONS. Cross-round synthesis: bytes are
// minimal (R19: FETCH 199/WRITE 407) yet rate is stuck at ~3.5-4.5 TB/s while
// fill/copy hit 6.3-7.0. The untested structural difference: our global instrs
// each touch 16 disjoint 64B chunks at 768B stride; copy's touch one 1KB span.
// A strip (16 rows x 768B) IS contiguous -> per block (4 waves): 12 x 1KB
// contiguous loads -> LDS x-bounce (784B-padded rows) -> fragment ds_reads +
// cvt (R13 k-map, Wfrag unchanged) -> MFMA (W in regs, 3 cts/wave) -> +bias
// -> LDS out-bounce -> 12 x 1KB contiguous stores. No 4x load replication
// (R19's flaw). Addressing strip-invariant, hoisted. 1-deep prefetch: next
// strip's 3 loads issued before this strip's stores -> the bounce-write's
// vmcnt(3) never waits store acks. (256,1) => 256 cap (ledger; R19: 108 clean).
__global__ __launch_bounds__(256, 1) void gemm_kernel(
    const float* __restrict__ x,
    const unsigned short* __restrict__ Wfrag,
    const float* __restrict__ bias,
    float* __restrict__ out, int nstrips, int spb) {
  __shared__ unsigned char xb[16 * 784];   // 12544 B, rows padded 768->784
  __shared__ unsigned char ob[16 * 784];   // 12544 B
  const int tid  = threadIdx.x;
  const int lane = tid & 63;
  const int wid  = tid >> 6;          // 0..3 -> owns cts [3*wid, 3*wid+3)
  const int l15  = lane & 15;
  const int lhi  = lane >> 4;

  // This wave's 18 W fragments in registers (one-time, L2-resident).
  short8 wf[3][6];
  #pragma unroll
  for (int t = 0; t < 3; ++t)
    #pragma unroll
    for (int c = 0; c < 6; ++c)
      wf[t][c] = *(const short8*)(Wfrag + (((wid * 3 + t) * 6 + c) * 64 + lane) * 8);

  // bias for this lane's 4 output features (oc = lhi*4+r, ct-independent)
  const f32x4 bias4 = *(const f32x4*)(bias + lhi * 4);

  // Hoisted strip-invariant addressing.
  // Contiguous-chunk index for this lane's 3 global instrs: idx in [0,768).
  int goff[3], coff[3];   // global byte offset within strip; LDS byte offset
  #pragma unroll
  for (int t = 0; t < 3; ++t) {
    int idx = ((wid * 3 + t) << 6) + lane;          // (instr)*64 + lane
    int row = idx / 48;                             // 48 chunks of 16B per 768B row
    int cb  = idx - row * 48;
    goff[t] = idx << 4;
    coff[t] = row * 784 + (cb << 4);
  }
  // Fragment-read offsets into xb: row l15, c-window c: +c*128+lhi*16 (+64).
  const int fbase = l15 * 784 + lhi * 16;
  // Out-bounce write offsets: row l15, float col (3*wid+t)*16 + lhi*4.
  int obw[3];
  #pragma unroll
  for (int t = 0; t < 3; ++t) obw[t] = l15 * 784 + (wid * 3 + t) * 64 + lhi * 16;

  int strip = blockIdx.x * spb;
  const int send = min(strip + spb, nstrips);
  if (strip >= send) return;

  // Prologue: issue strip 0's contiguous loads.
  f32x4 pre[3];
  {
    const unsigned char* xs = (const unsigned char*)x + (size_t)strip * 12288;
    #pragma unroll
    for (int t = 0; t < 3; ++t) pre[t] = *(const f32x4*)(xs + goff[t]);
  }

  while (strip < send) {
    // Deposit this strip's x into the bounce (vmcnt(3): prefetch loads are
    // OLDER than last strip's stores -> never waits store acks).
    #pragma unroll
    for (int t = 0; t < 3; ++t) *(f32x4*)(xb + coff[t]) = pre[t];
    __syncthreads();

    // Fragment reads + cvt (R13 k-map).
    short8 abf[6];
    #pragma unroll
    for (int c = 0; c < 6; ++c) {
      f32x4 lo = *(const f32x4*)(xb + fbase + c * 128);
      f32x4 hi = *(const f32x4*)(xb + fbase + c * 128 + 64);
      short8 v;
      #pragma unroll
      for (int e = 0; e < 4; ++e) {
        v[e]     = (short)f2bf(lo[e]);
        v[e + 4] = (short)f2bf(hi[e]);
      }
      abf[c] = v;
    }

    // Prefetch next strip's contiguous loads (in flight through MFMA+stores).
    const int nxt = strip + 1;
    if (nxt < send) {
      const unsigned char* xs = (const unsigned char*)x + (size_t)nxt * 12288;
      #pragma unroll
      for (int t = 0; t < 3; ++t) pre[t] = *(const f32x4*)(xs + goff[t]);
    }

    // MFMA: this wave's 3 cts; results (+bias) into the out-bounce.
    #pragma unroll
    for (int t = 0; t < 3; ++t) {
      f32x4 acc = {0.f, 0.f, 0.f, 0.f};
      #pragma unroll
      for (int c = 0; c < 6; ++c)
        acc = __builtin_amdgcn_mfma_f32_16x16x32_bf16(wf[t][c], abf[c], acc, 0, 0, 0);
      f32x4 res = {acc[0] + bias4[0], acc[1] + bias4[1],
                   acc[2] + bias4[2], acc[3] + bias4[3]};
      *(f32x4*)(ob + obw[t]) = res;
    }
    __syncthreads();

    // Contiguous stores: 12 x 1KB per block (3 per wave), copy-shaped.
    {
      unsigned char* os = (unsigned char*)out + (size_t)strip * 12288;
      #pragma unroll
      for (int t = 0; t < 3; ++t) {
        f32x4 v = *(const f32x4*)(ob + coff[t]);
        *(f32x4*)(os + goff[t]) = v;
      }
    }
    __syncthreads();   // bounce buffers free for next strip
    strip = nxt;
  }
}

extern "C" void kernel_launch(void* const* d_in, const int* in_sizes, int n_in,
                              void* d_out, int out_size, void* d_ws, size_t ws_size,
                              hipStream_t stream) {
    const float* x      = (const float*)d_in[0];
    const float* kern   = (const float*)d_in[1];
    const float* bias   = (const float*)d_in[2];
    const int*   cayley = (const int*)d_in[3];
    const int*   inv    = (const int*)d_in[4];
    float* out = (float*)d_out;
    unsigned short* Wfrag = (unsigned short*)d_ws;   // 73728 bytes

    const int nrows = in_sizes[0] / 192;
    const int nstrips = nrows / 16;                  // 32768

    build_w_kernel<<<(192 * 192 + 255) / 256, 256, 0, stream>>>(kern, cayley, inv, Wfrag);

    const int nblocks = 2048;                        // 16 strips per block
    const int spb     = (nstrips + nblocks - 1) / nblocks;
    gemm_kernel<<<nblocks, 256, 0, stream>>>(x, Wfrag, bias, out, nstrips, spb);
}